// Round 1
// baseline (344.655 us; speedup 1.0000x reference)
//
#include <hip/hip_runtime.h>

// Histogram1D: triangular-kernel soft histogram, 100 bins over [0,1], row-normalized.
// x: [32, 1048576] f32. out: [32, 100] f32.
// Each element contributes to exactly 2 adjacent bins:
//   u = x*100 - 0.5; i0 = floor(u); w = u - i0
//   bin i0   += (1-w)   [skipped if i0 < 0]
//   bin i0+1 += w       [skipped if i0+1 > 99]
// (in units of DELTA; the final normalize applies DELTA so EPS matches the ref.)

#define BINS 100
#define BATCH 32
#define NPER 1048576
#define TPB 256
#define BLOCKS_PER_ROW 64
#define CHUNK (NPER / BLOCKS_PER_ROW)          // 16384 elements per block
#define F4_PER_THREAD (CHUNK / 4 / TPB)        // 16 float4 per thread

__global__ __launch_bounds__(TPB) void hist_kernel(const float* __restrict__ x,
                                                   float* __restrict__ acc) {
    // per-wave privatized histograms to cut LDS atomic contention
    __shared__ float sh[4 * BINS];
    const int tid = threadIdx.x;
    for (int i = tid; i < 4 * BINS; i += TPB) sh[i] = 0.0f;
    __syncthreads();

    const int row  = blockIdx.y;
    const int blk  = blockIdx.x;
    const int wave = tid >> 6;
    float* hist = sh + wave * BINS;

    const float4* src = reinterpret_cast<const float4*>(
        x + (size_t)row * NPER + (size_t)blk * CHUNK);

#pragma unroll
    for (int k = 0; k < F4_PER_THREAD; ++k) {
        float4 v = src[k * TPB + tid];
        float vv[4] = {v.x, v.y, v.z, v.w};
#pragma unroll
        for (int e = 0; e < 4; ++e) {
            float u  = vv[e] * (float)BINS - 0.5f;
            float fi = floorf(u);               // exact; i0 in [-1, 99]
            float w  = u - fi;                  // [0,1)
            int   i0 = (int)fi;
            if (i0 >= 0)        atomicAdd(&hist[i0], 1.0f - w);   // ds_add_f32
            if (i0 + 1 < BINS)  atomicAdd(&hist[i0 + 1], w);
        }
    }
    __syncthreads();

    if (tid < BINS) {
        float s = sh[tid] + sh[BINS + tid] + sh[2 * BINS + tid] + sh[3 * BINS + tid];
        unsafeAtomicAdd(&acc[row * BINS + tid], s);   // global_atomic_add_f32
    }
}

// In-place normalize: acc (w-units) -> DELTA*acc / (DELTA*rowsum + EPS).
// One 64-thread wave per row; each thread owns bins t and t+64.
__global__ __launch_bounds__(64) void norm_kernel(float* __restrict__ acc) {
    const int row = blockIdx.x;
    const int t   = threadIdx.x;
    float v0 = (t < BINS)      ? acc[row * BINS + t]      : 0.0f;
    float v1 = (t + 64 < BINS) ? acc[row * BINS + t + 64] : 0.0f;
    float s  = v0 + v1;
#pragma unroll
    for (int off = 32; off > 0; off >>= 1) s += __shfl_down(s, off);
    s = __shfl(s, 0);
    const float DELTA = 0.01f;
    const float inv_denom = 1.0f / (DELTA * s + 1e-5f);
    if (t < BINS)      acc[row * BINS + t]      = (DELTA * v0) * inv_denom;
    if (t + 64 < BINS) acc[row * BINS + t + 64] = (DELTA * v1) * inv_denom;
}

extern "C" void kernel_launch(void* const* d_in, const int* in_sizes, int n_in,
                              void* d_out, int out_size, void* d_ws, size_t ws_size,
                              hipStream_t stream) {
    const float* x = (const float*)d_in[0];
    float* out = (float*)d_out;   // used as the accumulator, normalized in place

    hipMemsetAsync(out, 0, (size_t)BATCH * BINS * sizeof(float), stream);
    hist_kernel<<<dim3(BLOCKS_PER_ROW, BATCH), TPB, 0, stream>>>(x, out);
    norm_kernel<<<BATCH, 64, 0, stream>>>(out);
}